// Round 5
// baseline (81.985 us; speedup 1.0000x reference)
//
#include <hip/hip_runtime.h>

#define B_DIM 64
#define S_LEN 2048
#define H_DIM 256
#define TWO_PI 6.283185307179586f

typedef float f32x4 __attribute__((ext_vector_type(4)));

// Pass 1: per (b, split) partial reductions of S0 = sum_t x, C1 = sum_t x*cos,
// S1 = sum_t x*sin. Block: 256 threads = 4 waves. Each wave owns a contiguous
// run of rows_per_split/4 rows (16 KB when nsplit=32) and processes 2 rows per
// iteration with two independent float4 loads in flight.
__global__ __launch_bounds__(256) void k_partial(const float* __restrict__ x,
                                                 float* __restrict__ partials,
                                                 int rows_per_split, int nsplit_b) {
    const int b = blockIdx.x;
    const int split = blockIdx.y;
    const int tid = threadIdx.x;
    const int lane = tid & 63;
    const int wave = tid >> 6;
    const int h0 = lane * 4;

    const int rows_per_wave = rows_per_split >> 2;      // always even (>=16)
    const int t0 = split * rows_per_split + wave * rows_per_wave;
    const float* px = x + ((size_t)b * S_LEN + t0) * H_DIM + h0;
    const float wfreq = TWO_PI / (float)S_LEN;

    f32x4 s0v = {0.f, 0.f, 0.f, 0.f};
    f32x4 c1v = {0.f, 0.f, 0.f, 0.f};
    f32x4 s1v = {0.f, 0.f, 0.f, 0.f};

    for (int r = 0; r < rows_per_wave; r += 2) {
        const f32x4 v0 = *reinterpret_cast<const f32x4*>(px + (size_t)r * H_DIM);
        const f32x4 v1 = *reinterpret_cast<const f32x4*>(px + (size_t)(r + 1) * H_DIM);
        float sn0, cs0, sn1, cs1;
        __sincosf(wfreq * (float)(t0 + r), &sn0, &cs0);
        __sincosf(wfreq * (float)(t0 + r + 1), &sn1, &cs1);
        s0v += v0 + v1;
        c1v += v0 * cs0 + v1 * cs1;
        s1v += v0 * sn0 + v1 * sn1;
    }

    __shared__ float red[4][3 * H_DIM];
#pragma unroll
    for (int j = 0; j < 4; ++j) {
        red[wave][0 * H_DIM + h0 + j] = s0v[j];
        red[wave][1 * H_DIM + h0 + j] = c1v[j];
        red[wave][2 * H_DIM + h0 + j] = s1v[j];
    }
    __syncthreads();

    // 768 values (3 comps x 256 h); each of 256 threads reduces 3 across 4 waves.
#pragma unroll
    for (int k = 0; k < 3; ++k) {
        const int v = tid + k * 256;
        const float acc = red[0][v] + red[1][v] + red[2][v] + red[3][v];
        partials[((size_t)(split * B_DIM + b)) * (3 * H_DIM) + v] = acc;
    }
}

// Pass 2: reduce the nsplit partials -> sums[b][3*256]
__global__ __launch_bounds__(256) void k_reduce(const float* __restrict__ partials,
                                                float* __restrict__ sums,
                                                int nsplit) {
    const int j = blockIdx.x * 256 + threadIdx.x;  // < B*768
    float acc = 0.f;
    for (int s = 0; s < nsplit; ++s)
        acc += partials[(size_t)s * (B_DIM * 3 * H_DIM) + j];
    sums[j] = acc;
}

// Pass 3: fused low-pass reconstruction + residual + LayerNorm.
// Block: 256 threads = 4 waves; block covers 32 rows (8 contiguous rows/wave).
// No LDS / no __syncthreads: each lane direct-loads its float4 slice of the
// per-b sums and the H-params (L1/L2 broadcast). out stores are non-temporal
// so the 128 MB write stream doesn't evict x from L3 (x re-read stays cached).
#define FROWS 32
__global__ __launch_bounds__(256) void k_final(const float* __restrict__ x,
                                               const float* __restrict__ sums,
                                               const float* __restrict__ sqrt_beta,
                                               const float* __restrict__ lnw,
                                               const float* __restrict__ lnb,
                                               float* __restrict__ out) {
    const int blocks_per_b = S_LEN / FROWS;   // 64
    const int b = blockIdx.x / blocks_per_b;
    const int tchunk = blockIdx.x % blocks_per_b;
    const int tid = threadIdx.x;
    const int lane = tid & 63;
    const int wave = tid >> 6;
    const int h0 = lane * 4;

    const f32x4 S0 = *reinterpret_cast<const f32x4*>(sums + b * 768 + h0);
    const f32x4 C1 = *reinterpret_cast<const f32x4*>(sums + b * 768 + 256 + h0);
    const f32x4 S1 = *reinterpret_cast<const f32x4*>(sums + b * 768 + 512 + h0);
    const f32x4 sb = *reinterpret_cast<const f32x4*>(sqrt_beta + h0);
    const f32x4 Wv = *reinterpret_cast<const f32x4*>(lnw + h0);
    const f32x4 Bv = *reinterpret_cast<const f32x4*>(lnb + h0);
    const f32x4 b2 = sb * sb;
    const f32x4 CA = b2 + 1.f;        // coefficient on x
    const f32x4 CB = 1.f - b2;        // coefficient on low_pass

    const float invS = 1.f / (float)S_LEN;
    const float wfreq = TWO_PI / (float)S_LEN;
    const int tbase = tchunk * FROWS + wave * (FROWS / 4);
    const float* __restrict__ pxr = x + ((size_t)b * S_LEN + tbase) * H_DIM + h0;
    float* __restrict__ por = out + ((size_t)b * S_LEN + tbase) * H_DIM + h0;

#pragma unroll
    for (int r = 0; r < FROWS / 4; ++r) {
        float sn, cs;
        __sincosf(wfreq * (float)(tbase + r), &sn, &cs);

        const f32x4 v = *reinterpret_cast<const f32x4*>(pxr + (size_t)r * H_DIM);
        // low-pass reconstruction + residual mix
        const f32x4 lp = (S0 + (C1 * cs + S1 * sn) * 2.f) * invS;
        const f32x4 y = CB * lp + CA * v;

        float sum = y.x + y.y + y.z + y.w;
        float sumsq = y.x * y.x + y.y * y.y + y.z * y.z + y.w * y.w;
#pragma unroll
        for (int m = 1; m < 64; m <<= 1) {
            sum += __shfl_xor(sum, m, 64);
            sumsq += __shfl_xor(sumsq, m, 64);
        }
        const float mean = sum * (1.f / (float)H_DIM);
        const float var = sumsq * (1.f / (float)H_DIM) - mean * mean;
        const float rstd = rsqrtf(var + 1e-5f);

        f32x4 o = (y - mean) * rstd * Wv + Bv;
        __builtin_nontemporal_store(o, reinterpret_cast<f32x4*>(por + (size_t)r * H_DIM));
    }
}

extern "C" void kernel_launch(void* const* d_in, const int* in_sizes, int n_in,
                              void* d_out, int out_size, void* d_ws, size_t ws_size,
                              hipStream_t stream) {
    const float* x  = (const float*)d_in[0];
    const float* sb = (const float*)d_in[1];
    const float* w  = (const float*)d_in[2];
    const float* bi = (const float*)d_in[3];
    float* out = (float*)d_out;

    // workspace: partials [nsplit][B][3*H] fp32 + sums [B][3*H] fp32
    int nsplit = 32;
    while (nsplit > 1 &&
           ((size_t)(nsplit + 1) * B_DIM * 3 * H_DIM * sizeof(float)) > ws_size)
        nsplit >>= 1;
    float* partials = (float*)d_ws;
    float* sums = partials + (size_t)nsplit * B_DIM * 3 * H_DIM;

    k_partial<<<dim3(B_DIM, nsplit), 256, 0, stream>>>(x, partials, S_LEN / nsplit, nsplit);
    k_reduce<<<(B_DIM * 3 * H_DIM) / 256, 256, 0, stream>>>(partials, sums, nsplit);
    k_final<<<B_DIM * (S_LEN / FROWS), 256, 0, stream>>>(x, sums, sb, w, bi, out);
}